// Round 6
// baseline (245.411 us; speedup 1.0000x reference)
//
#include <hip/hip_runtime.h>
#include <cstdint>
#include <cstddef>

// ---------------------------------------------------------------------------
// Attention block, MI355X. fp32 in/out, f16 MFMA internal (fp32 accumulate).
//   kv = x_prev @ w_kv ; q = x @ w_q ; flash attention per (b,h) ; out proj.
// Shapes: b=4, n=2048, DIM=512, H=8, D=64, INNER=512.
// ---------------------------------------------------------------------------

#define BATCH 4
#define SEQ   2048
#define NHEAD 8
#define DHEAD 64
#define MROWS (BATCH * SEQ)   // 8192
#define KDIM  512
#define NQKV  1536
#define LDQKV 1536
#define SCALE 0.125f

typedef _Float16 half_t;
typedef _Float16 half8  __attribute__((ext_vector_type(8)));
typedef _Float16 half4v __attribute__((ext_vector_type(4)));
typedef float    float4v __attribute__((ext_vector_type(4)));

// 2^x via hardware op (guarded builtin name; inline-asm fallback)
__device__ inline float fast_exp2(float x) {
#if __has_builtin(__builtin_amdgcn_exp2f)
  return __builtin_amdgcn_exp2f(x);
#else
  float r; asm("v_exp_f32 %0, %1" : "=v"(r) : "v"(x)); return r;
#endif
}

// global (AS1) -> LDS (AS3) direct 16B copy; dest is wave-uniform base + lane*16
__device__ inline void load_lds16(const half_t* g, half_t* l) {
  __builtin_amdgcn_global_load_lds(
      (const __attribute__((address_space(1))) void*)g,
      (__attribute__((address_space(3))) void*)l, 16, 0, 0);
}

// ---------------------------------------------------------------------------
// fp32 -> f16 elementwise convert (vectorized, n4 = n/4)
__global__ __launch_bounds__(256) void cvt_f32_f16(const float* __restrict__ in,
                                                   half_t* __restrict__ out, int n4) {
  int i = blockIdx.x * 256 + threadIdx.x;
  if (i < n4) {
    float4v v = *(const float4v*)(in + (size_t)i * 4);
    half4v h;
    h[0] = (half_t)v[0]; h[1] = (half_t)v[1];
    h[2] = (half_t)v[2]; h[3] = (half_t)v[3];
    *(half4v*)(out + (size_t)i * 4) = h;
  }
}

// transpose+convert weight [K=512][N] -> [N][512] f16. grid = N*512/256 blocks.
__global__ __launch_bounds__(256) void tcvt(const float* __restrict__ in,
                                            half_t* __restrict__ out, int N) {
  int idx = blockIdx.x * 256 + threadIdx.x;  // idx over N*512 outputs
  int nr = idx >> 9;        // output row (0..N)
  int kc = idx & 511;       // output col = input row
  out[idx] = (half_t)in[(size_t)kc * N + nr];
}

// ---------------------------------------------------------------------------
// GEMM-BT: C[M x Ncols] = A[M x 512] * Bt[Ncols x 512]^T   (f16 in, fp32 acc)
// 128x128 tile, BK=64, 256 threads = 4 waves (2x2), wave = 64x64 out.
// MODE 0: QKV projection -> f16 C [8192][1536] (A switches per column region)
// MODE 1: out projection -> fp32 C [8192][512] + bias
// (No setprio here: null on barrier-lockstep GEMM structures per m190.)
template <int MODE>
__global__ __launch_bounds__(256) void gemm_bt(
    const half_t* __restrict__ A0, const half_t* __restrict__ A1,
    const half_t* __restrict__ B0, const half_t* __restrict__ B1,
    half_t* __restrict__ Ch, const float* __restrict__ bias,
    float* __restrict__ Cf)
{
  __shared__ half_t As[128 * 64];
  __shared__ half_t Bs[128 * 64];

  const int bm = blockIdx.x, bn = blockIdx.y;
  const int tid = threadIdx.x;
  const int w = tid >> 6, lane = tid & 63;
  const int l15 = lane & 15, lhi = lane >> 4;
  const int wm = w >> 1, wn = w & 1;

  const half_t* A;
  const half_t* Bt;
  if (MODE == 0) {
    if (bn < 4) { A = A0; Bt = B0 + (size_t)bn * 128 * 512; }
    else        { A = A1; Bt = B1 + (size_t)(bn - 4) * 128 * 512; }
  } else {
    A = A0; Bt = B0 + (size_t)bn * 128 * 512;
  }

  // staging: per wave 32 rows of each tile, 4 calls x (64 lanes * 16B = 8 rows)
  const int srow = (w << 5) + (lane >> 3);   // row within tile this lane loads
  const int sch  = lane & 7;                 // 16B chunk within 128B row
  const half_t* aSrc = A  + (size_t)(bm * 128 + srow) * 512 + sch * 8;
  const half_t* bSrc = Bt + (size_t)srow * 512 + sch * 8;

  float4v acc[4][4];
  #pragma unroll
  for (int i = 0; i < 4; ++i)
    #pragma unroll
    for (int j = 0; j < 4; ++j) acc[i][j] = (float4v)0.0f;

  for (int kt = 0; kt < 8; ++kt) {
    const int ko = kt * 64;
    #pragma unroll
    for (int c = 0; c < 4; ++c) {
      load_lds16(aSrc + (size_t)c * 8 * 512 + ko, &As[((w << 5) + c * 8) * 64]);
      load_lds16(bSrc + (size_t)c * 8 * 512 + ko, &Bs[((w << 5) + c * 8) * 64]);
    }
    __syncthreads();   // drains vmcnt (global_load_lds) before compute

    #pragma unroll
    for (int kk = 0; kk < 2; ++kk) {
      const int kof = kk * 32 + lhi * 8;
      half8 af[4], bf[4];
      #pragma unroll
      for (int mf = 0; mf < 4; ++mf)
        af[mf] = *(const half8*)&As[(wm * 64 + mf * 16 + l15) * 64 + kof];
      #pragma unroll
      for (int nf = 0; nf < 4; ++nf)
        bf[nf] = *(const half8*)&Bs[(wn * 64 + nf * 16 + l15) * 64 + kof];
      #pragma unroll
      for (int mf = 0; mf < 4; ++mf)
        #pragma unroll
        for (int nf = 0; nf < 4; ++nf)
          acc[mf][nf] = __builtin_amdgcn_mfma_f32_16x16x32_f16(
              af[mf], bf[nf], acc[mf][nf], 0, 0, 0);
    }
    __syncthreads();
  }

  // epilogue: C/D layout col=lane&15, row=(lane>>4)*4+reg
  #pragma unroll
  for (int mf = 0; mf < 4; ++mf)
    #pragma unroll
    for (int nf = 0; nf < 4; ++nf)
      #pragma unroll
      for (int r = 0; r < 4; ++r) {
        const int row = bm * 128 + wm * 64 + mf * 16 + lhi * 4 + r;
        const int col = bn * 128 + wn * 64 + nf * 16 + l15;
        if (MODE == 0)
          Ch[(size_t)row * LDQKV + col] = (half_t)acc[mf][nf][r];
        else
          Cf[(size_t)row * 512 + col] = acc[mf][nf][r] + bias[col];
      }
}

// ---------------------------------------------------------------------------
// Flash attention, 2-phase pipelined (T3/T14) + T5 setprio on MFMA clusters.
// Block = 128 q rows, one (b,h). 256 thr = 4 waves; each wave owns 32 q rows
// (sub-blocks mb=0,1). KV tile 64.
// Per iter: issue K(t+1) gload_lds + V(t+1) reg loads into NXT buffers ->
// compute tile t from CUR -> scatter V(t+1) regs -> ONE __syncthreads -> swap.
// K-load latency hides under compute; barrier count halves vs naive.
// Q/K LDS XOR-swizzled: chunk' = chunk ^ (row&7) (16B chunks in 128B rows).
// Vt LDS swizzle: chunk' = chunk ^ (d&7) ^ (d>>3)  -- the (d>>3) term makes
//   the scatter-WRITE conflict-free (else f is wave-uniform per write inst
//   -> 8-way bank conflict; with it, all 32 banks covered, residual 2
//   lanes/bank write adjacent halves of one dword).
__global__ __launch_bounds__(256) void attn_fwd(const half_t* __restrict__ qkv,
                                                half_t* __restrict__ o)
{
  __shared__ half_t Qs[128 * 64];
  __shared__ half_t KsBuf[2][64 * 64];
  __shared__ half_t VtBuf[2][64 * 64];   // V transposed: [d][kv]
  __shared__ half_t Ps[4][32 * 64];      // per-wave P tile (32 q rows)

  const int qt = blockIdx.x;             // q tile (0..15), 128 rows each
  const int bh = blockIdx.y;             // 0..31
  const int b = bh >> 3, h = bh & 7;
  const int tid = threadIdx.x;
  const int w = tid >> 6, lane = tid & 63;
  const int l15 = lane & 15, lhi = lane >> 4;

  const half_t* base = qkv + (size_t)(b * SEQ) * LDQKV;
  const int colq = h * 64;
  const int colk = 512 + h * 64;
  const int colv = 1024 + h * 64;

  const int srow_l = lane >> 3;          // staging row-within-8 for this lane
  const int sch = lane & 7;              // staging 16B chunk for this lane

  // V reg-load geometry: 512 slots = 64 rows x 8 chunks, 2 slots/thread
  const int vr0 = tid >> 3, vch = tid & 7;       // slot s2=0: row, chunk
  const int vr1 = (256 + tid) >> 3;              // slot s2=1 row (chunk same)

  // ---- prologue: issue Q (once) + K(0); load V(0) regs; scatter; barrier
  #pragma unroll
  for (int c = 0; c < 4; ++c) {
    const int row = w * 32 + c * 8 + srow_l;
    const int cs = sch ^ (row & 7);
    load_lds16(base + (size_t)(qt * 128 + row) * LDQKV + colq + cs * 8,
               &Qs[(w * 32 + c * 8) * 64]);
  }
  half_t* ksc = KsBuf[0]; half_t* ksn = KsBuf[1];
  half_t* vtc = VtBuf[0]; half_t* vtn = VtBuf[1];
  #pragma unroll
  for (int c = 0; c < 2; ++c) {
    const int row = w * 16 + c * 8 + srow_l;
    const int cs = sch ^ (row & 7);
    load_lds16(base + (size_t)(0 * 64 + row) * LDQKV + colk + cs * 8,
               &ksc[(w * 16 + c * 8) * 64]);
  }
  {
    half8 v0 = *(const half8*)(base + (size_t)vr0 * LDQKV + colv + vch * 8);
    half8 v1 = *(const half8*)(base + (size_t)vr1 * LDQKV + colv + vch * 8);
    #pragma unroll
    for (int j = 0; j < 8; ++j) {
      const int d = vch * 8 + j;
      const int fx = (d & 7) ^ (d >> 3);
      vtc[d * 64 + (((vr0 >> 3) ^ fx) << 3) + (vr0 & 7)] = v0[j];
      vtc[d * 64 + (((vr1 >> 3) ^ fx) << 3) + (vr1 & 7)] = v1[j];
    }
  }
  __syncthreads();

  // Q fragments are loop-invariant: hoist. Wave rows = w*32 + mb*16 + l15.
  half8 qf[2][2];
  #pragma unroll
  for (int mb = 0; mb < 2; ++mb)
    #pragma unroll
    for (int kk = 0; kk < 2; ++kk) {
      const int row = w * 32 + mb * 16 + l15;
      const int cr = kk * 4 + lhi;
      qf[mb][kk] = *(const half8*)&Qs[row * 64 + (cr ^ (row & 7)) * 8];
    }

  float m_s[2][4], l_s[2][4];
  float4v acc[2][4];
  #pragma unroll
  for (int mb = 0; mb < 2; ++mb) {
    #pragma unroll
    for (int r = 0; r < 4; ++r) { m_s[mb][r] = -3.0e38f; l_s[mb][r] = 0.0f; }
    #pragma unroll
    for (int nf = 0; nf < 4; ++nf) acc[mb][nf] = (float4v)0.0f;
  }

  const float sc = SCALE * 1.44269504089f;   // fold softmax scale, exp2 domain

  for (int t = 0; t < 32; ++t) {
    // ---- issue next tile's staging into NXT buffers (hidden under compute)
    half8 vp0, vp1;
    if (t < 31) {
      const size_t nb = (size_t)((t + 1) * 64);
      vp0 = *(const half8*)(base + (nb + vr0) * LDQKV + colv + vch * 8);
      vp1 = *(const half8*)(base + (nb + vr1) * LDQKV + colv + vch * 8);
      #pragma unroll
      for (int c = 0; c < 2; ++c) {
        const int row = w * 16 + c * 8 + srow_l;
        const int cs = sch ^ (row & 7);
        load_lds16(base + (nb + row) * LDQKV + colk + cs * 8,
                   &ksn[(w * 16 + c * 8) * 64]);
      }
    }

    // ---- S = Q K^T (per wave: 32 q rows x 64 keys; kf reused across mb)
    float4v s[2][4];
    #pragma unroll
    for (int mb = 0; mb < 2; ++mb)
      #pragma unroll
      for (int nf = 0; nf < 4; ++nf) s[mb][nf] = (float4v)0.0f;
    __builtin_amdgcn_s_setprio(1);    // T5: favor this wave's matrix phase
    #pragma unroll
    for (int kk = 0; kk < 2; ++kk) {
      const int cr = kk * 4 + lhi;
      #pragma unroll
      for (int nf = 0; nf < 4; ++nf) {
        const int row = nf * 16 + l15;
        half8 kf = *(const half8*)&ksc[row * 64 + (cr ^ (row & 7)) * 8];
        #pragma unroll
        for (int mb = 0; mb < 2; ++mb)
          s[mb][nf] = __builtin_amdgcn_mfma_f32_16x16x32_f16(
              qf[mb][kk], kf, s[mb][nf], 0, 0, 0);
      }
    }
    __builtin_amdgcn_s_setprio(0);

    // ---- online softmax per mb (rows spread over 16 lanes; shfl_xor reduce)
    #pragma unroll
    for (int mb = 0; mb < 2; ++mb) {
      float rmax[4], rsum[4], mnew[4], alpha[4];
      #pragma unroll
      for (int nf = 0; nf < 4; ++nf)
        #pragma unroll
        for (int r = 0; r < 4; ++r) s[mb][nf][r] *= sc;
      #pragma unroll
      for (int r = 0; r < 4; ++r) {
        rmax[r] = fmaxf(fmaxf(s[mb][0][r], s[mb][1][r]),
                        fmaxf(s[mb][2][r], s[mb][3][r]));
        #pragma unroll
        for (int off = 1; off < 16; off <<= 1)
          rmax[r] = fmaxf(rmax[r], __shfl_xor(rmax[r], off));
        mnew[r] = fmaxf(m_s[mb][r], rmax[r]);
        alpha[r] = fast_exp2(m_s[mb][r] - mnew[r]);
        m_s[mb][r] = mnew[r];
      }
      #pragma unroll
      for (int nf = 0; nf < 4; ++nf)
        #pragma unroll
        for (int r = 0; r < 4; ++r)
          s[mb][nf][r] = fast_exp2(s[mb][nf][r] - mnew[r]);
      #pragma unroll
      for (int r = 0; r < 4; ++r) {
        rsum[r] = (s[mb][0][r] + s[mb][1][r]) + (s[mb][2][r] + s[mb][3][r]);
        #pragma unroll
        for (int off = 1; off < 16; off <<= 1)
          rsum[r] += __shfl_xor(rsum[r], off);
        l_s[mb][r] = l_s[mb][r] * alpha[r] + rsum[r];
      }
      #pragma unroll
      for (int nf = 0; nf < 4; ++nf)
        #pragma unroll
        for (int r = 0; r < 4; ++r) acc[mb][nf][r] *= alpha[r];

      // ---- P -> f16 -> per-wave LDS (swizzled); pr = mb*16 + lhi*4 + r
      #pragma unroll
      for (int nf = 0; nf < 4; ++nf)
        #pragma unroll
        for (int r = 0; r < 4; ++r) {
          const int pr = mb * 16 + lhi * 4 + r;
          const int col = nf * 16 + l15;
          Ps[w][pr * 64 + (((col >> 3) ^ (pr & 7)) << 3) + (col & 7)] =
              (half_t)s[mb][nf][r];
        }
    }
    asm volatile("s_waitcnt lgkmcnt(0)" ::: "memory");  // own-wave P visible

    // ---- PV: acc[mb][nf] += P[mb] * Vt  (vf reused across mb)
    __builtin_amdgcn_s_setprio(1);    // T5
    #pragma unroll
    for (int kk = 0; kk < 2; ++kk) {
      const int cr = kk * 4 + lhi;
      half8 pf[2];
      #pragma unroll
      for (int mb = 0; mb < 2; ++mb) {
        const int prow = mb * 16 + l15;
        pf[mb] = *(const half8*)&Ps[w][prow * 64 + (cr ^ (prow & 7)) * 8];
      }
      #pragma unroll
      for (int nf = 0; nf < 4; ++nf) {
        const int d = nf * 16 + l15;
        half8 vf = *(const half8*)&vtc[d * 64 + ((cr ^ (d & 7) ^ (d >> 3)) << 3)];
        #pragma unroll
        for (int mb = 0; mb < 2; ++mb)
          acc[mb][nf] = __builtin_amdgcn_mfma_f32_16x16x32_f16(
              pf[mb], vf, acc[mb][nf], 0, 0, 0);
      }
    }
    __builtin_amdgcn_s_setprio(0);

    // ---- scatter prefetched V(t+1) into NXT (other buffer: no reader race)
    if (t < 31) {
      #pragma unroll
      for (int j = 0; j < 8; ++j) {
        const int d = vch * 8 + j;
        const int fx = (d & 7) ^ (d >> 3);
        vtn[d * 64 + (((vr0 >> 3) ^ fx) << 3) + (vr0 & 7)] = vp0[j];
        vtn[d * 64 + (((vr1 >> 3) ^ fx) << 3) + (vr1 & 7)] = vp1[j];
      }
    }
    __syncthreads();   // drains K(t+1) gload_lds + Vt writes; swap buffers
    half_t* tp = ksc; ksc = ksn; ksn = tp;
    tp = vtc; vtc = vtn; vtn = tp;
  }

  // ---- epilogue: O = acc / l  -> o_ws [8192][512] f16
  #pragma unroll
  for (int mb = 0; mb < 2; ++mb) {
    float inv[4];
    #pragma unroll
    for (int r = 0; r < 4; ++r) inv[r] = 1.0f / l_s[mb][r];
    #pragma unroll
    for (int nf = 0; nf < 4; ++nf)
      #pragma unroll
      for (int r = 0; r < 4; ++r) {
        const int grow = b * SEQ + qt * 128 + w * 32 + mb * 16 + lhi * 4 + r;
        const int col = h * 64 + nf * 16 + l15;
        o[(size_t)grow * 512 + col] = (half_t)(acc[mb][nf][r] * inv[r]);
      }
  }
}

// ---------------------------------------------------------------------------
extern "C" void kernel_launch(void* const* d_in, const int* in_sizes, int n_in,
                              void* d_out, int out_size, void* d_ws, size_t ws_size,
                              hipStream_t stream)
{
  const float* x   = (const float*)d_in[0];
  const float* xp  = (const float*)d_in[1];
  const float* wq  = (const float*)d_in[2];
  const float* wkv = (const float*)d_in[3];
  const float* wo  = (const float*)d_in[4];
  const float* bo  = (const float*)d_in[5];
  float* out = (float*)d_out;

  half_t* ws   = (half_t*)d_ws;
  half_t* xh   = ws;                   // [8192][512]
  half_t* xph  = xh   + 4194304;       // [8192][512]
  half_t* wqt  = xph  + 4194304;       // [512][512]   (w_q^T)
  half_t* wkvt = wqt  + 262144;        // [1024][512]  (w_kv^T)
  half_t* wot  = wkvt + 524288;        // [512][512]   (w_out^T)
  half_t* qkvc = wot  + 262144;        // [8192][1536] q|k|v
  half_t* ows  = qkvc + 12582912;      // [8192][512]  attention out
  // total ws use: 26,214,400 halfs = 52.4 MB

  cvt_f32_f16<<<4096, 256, 0, stream>>>(x,  xh,  1048576);
  cvt_f32_f16<<<4096, 256, 0, stream>>>(xp, xph, 1048576);
  tcvt<<<1024, 256, 0, stream>>>(wq,  wqt,  512);
  tcvt<<<2048, 256, 0, stream>>>(wkv, wkvt, 1024);
  tcvt<<<1024, 256, 0, stream>>>(wo,  wot,  512);

  gemm_bt<0><<<dim3(64, 12), 256, 0, stream>>>(xh, xph, wqt, wkvt, qkvc,
                                               nullptr, nullptr);
  attn_fwd<<<dim3(16, 32), 256, 0, stream>>>(qkvc, ows);
  gemm_bt<1><<<dim3(64, 4), 256, 0, stream>>>(ows, nullptr, wot, nullptr,
                                              nullptr, bo, out);
}

// Round 10
// 192.144 us; speedup vs baseline: 1.2772x; 1.2772x over previous
//
#include <hip/hip_runtime.h>
#include <cstdint>
#include <cstddef>

// ---------------------------------------------------------------------------
// Attention block, MI355X. fp32 in/out, f16 MFMA internal (fp32 accumulate).
//   kv = x_prev @ w_kv ; q = x @ w_q ; flash attention per (b,h) ; out proj.
// Shapes: b=4, n=2048, DIM=512, H=8, D=64, INNER=512.
// ---------------------------------------------------------------------------

#define BATCH 4
#define SEQ   2048
#define NHEAD 8
#define DHEAD 64
#define MROWS (BATCH * SEQ)   // 8192
#define KDIM  512
#define NQKV  1536
#define LDQKV 1536
#define SCALE 0.125f

typedef _Float16 half_t;
typedef _Float16 half8  __attribute__((ext_vector_type(8)));
typedef _Float16 half4v __attribute__((ext_vector_type(4)));
typedef _Float16 half2v __attribute__((ext_vector_type(2)));
typedef float    float4v __attribute__((ext_vector_type(4)));
typedef float    f32x16  __attribute__((ext_vector_type(16)));
typedef uint32_t u32;
typedef u32      u32x4   __attribute__((ext_vector_type(4)));

// 2^x via hardware op (guarded builtin name; inline-asm fallback)
__device__ inline float fast_exp2(float x) {
#if __has_builtin(__builtin_amdgcn_exp2f)
  return __builtin_amdgcn_exp2f(x);
#else
  float r; asm("v_exp_f32 %0, %1" : "=v"(r) : "v"(x)); return r;
#endif
}

// global (AS1) -> LDS (AS3) direct 16B copy; dest is wave-uniform base + lane*16
__device__ inline void load_lds16(const half_t* g, half_t* l) {
  __builtin_amdgcn_global_load_lds(
      (const __attribute__((address_space(1))) void*)g,
      (__attribute__((address_space(3))) void*)l, 16, 0, 0);
}

// ---------------------------------------------------------------------------
// fp32 -> f16 elementwise convert, two tensors fused (n4 = elems/4 per tensor)
__global__ __launch_bounds__(256) void cvt2_f32_f16(
    const float* __restrict__ a, const float* __restrict__ b,
    half_t* __restrict__ oa, half_t* __restrict__ ob, int n4) {
  int i = blockIdx.x * 256 + threadIdx.x;
  const float* in;  half_t* out;
  if (i < n4) { in = a; out = oa; }
  else        { in = b; out = ob; i -= n4; }
  float4v v = *(const float4v*)(in + (size_t)i * 4);
  half4v h;
  h[0] = (half_t)v[0]; h[1] = (half_t)v[1];
  h[2] = (half_t)v[2]; h[3] = (half_t)v[3];
  *(half4v*)(out + (size_t)i * 4) = h;
}

// transpose+convert weight [512][N] fp32 -> [N][512] f16, LDS-tiled so both
// global read (128B rows) and write (64B f16 rows) are coalesced.
// grid = (N/32, 16), block = 256 (32x8).
__global__ __launch_bounds__(256) void tcvt(const float* __restrict__ in,
                                            half_t* __restrict__ out, int N) {
  __shared__ float tile[32][33];            // +1 pad: conflict-free both sides
  const int n0 = blockIdx.x * 32;           // output-row / input-col base
  const int k0 = blockIdx.y * 32;           // input-row / output-col base
  const int tx = threadIdx.x & 31, ty = threadIdx.x >> 5;   // ty = 0..7
  #pragma unroll
  for (int i = 0; i < 4; ++i) {
    const int k = ty * 4 + i;
    tile[k][tx] = in[(size_t)(k0 + k) * N + n0 + tx];
  }
  __syncthreads();
  #pragma unroll
  for (int i = 0; i < 4; ++i) {
    const int n = ty * 4 + i;
    out[(size_t)(n0 + n) * 512 + k0 + tx] = (half_t)tile[tx][n];
  }
}

// ---------------------------------------------------------------------------
// GEMM-BT: C[M x Ncols] = A[M x 512] * Bt[Ncols x 512]^T   (f16 in, fp32 acc)
// 128x128 tile, BK=64, 256 threads = 4 waves (2x2), wave = 64x64 out.
// MODE 0: QKV projection -> f16 C [8192][1536] (A switches per column region)
// MODE 1: out projection -> fp32 C [8192][512] + bias
template <int MODE>
__global__ __launch_bounds__(256) void gemm_bt(
    const half_t* __restrict__ A0, const half_t* __restrict__ A1,
    const half_t* __restrict__ B0, const half_t* __restrict__ B1,
    half_t* __restrict__ Ch, const float* __restrict__ bias,
    float* __restrict__ Cf)
{
  __shared__ half_t As[128 * 64];
  __shared__ half_t Bs[128 * 64];

  const int bm = blockIdx.x, bn = blockIdx.y;
  const int tid = threadIdx.x;
  const int w = tid >> 6, lane = tid & 63;
  const int l15 = lane & 15, lhi = lane >> 4;
  const int wm = w >> 1, wn = w & 1;

  const half_t* A;
  const half_t* Bt;
  if (MODE == 0) {
    if (bn < 4) { A = A0; Bt = B0 + (size_t)bn * 128 * 512; }
    else        { A = A1; Bt = B1 + (size_t)(bn - 4) * 128 * 512; }
  } else {
    A = A0; Bt = B0 + (size_t)bn * 128 * 512;
  }

  const int srow = (w << 5) + (lane >> 3);
  const int sch  = lane & 7;
  const half_t* aSrc = A  + (size_t)(bm * 128 + srow) * 512 + sch * 8;
  const half_t* bSrc = Bt + (size_t)srow * 512 + sch * 8;

  float4v acc[4][4];
  #pragma unroll
  for (int i = 0; i < 4; ++i)
    #pragma unroll
    for (int j = 0; j < 4; ++j) acc[i][j] = (float4v)0.0f;

  for (int kt = 0; kt < 8; ++kt) {
    const int ko = kt * 64;
    #pragma unroll
    for (int c = 0; c < 4; ++c) {
      load_lds16(aSrc + (size_t)c * 8 * 512 + ko, &As[((w << 5) + c * 8) * 64]);
      load_lds16(bSrc + (size_t)c * 8 * 512 + ko, &Bs[((w << 5) + c * 8) * 64]);
    }
    __syncthreads();

    #pragma unroll
    for (int kk = 0; kk < 2; ++kk) {
      const int kof = kk * 32 + lhi * 8;
      half8 af[4], bf[4];
      #pragma unroll
      for (int mf = 0; mf < 4; ++mf)
        af[mf] = *(const half8*)&As[(wm * 64 + mf * 16 + l15) * 64 + kof];
      #pragma unroll
      for (int nf = 0; nf < 4; ++nf)
        bf[nf] = *(const half8*)&Bs[(wn * 64 + nf * 16 + l15) * 64 + kof];
      #pragma unroll
      for (int mf = 0; mf < 4; ++mf)
        #pragma unroll
        for (int nf = 0; nf < 4; ++nf)
          acc[mf][nf] = __builtin_amdgcn_mfma_f32_16x16x32_f16(
              af[mf], bf[nf], acc[mf][nf], 0, 0, 0);
    }
    __syncthreads();
  }

  #pragma unroll
  for (int mf = 0; mf < 4; ++mf)
    #pragma unroll
    for (int nf = 0; nf < 4; ++nf)
      #pragma unroll
      for (int r = 0; r < 4; ++r) {
        const int row = bm * 128 + wm * 64 + mf * 16 + lhi * 4 + r;
        const int col = bn * 128 + wn * 64 + nf * 16 + l15;
        if (MODE == 0)
          Ch[(size_t)row * LDQKV + col] = (half_t)acc[mf][nf][r];
        else
          Cf[(size_t)row * 512 + col] = acc[mf][nf][r] + bias[col];
      }
}

// ---------------------------------------------------------------------------
// Flash attention, swapped-QK^T 32x32x16 structure + 2-phase pipeline + T5
// setprio + T13 defer-max. Block = 128 q rows, one (b,h). 4 waves; wave owns
// 32 q rows. KV tile 64.
// Swapped S^T = mfma(K, Q): lane holds q = lane&31 as D-column -> softmax
// m/l/alpha are per-lane SCALARS; row-reduce = 31 reg ops + one shfl_xor(32).
// P packs to f16 in-register; cross-half k-exchange via 8 shfl_xor(32) +
// cndmask builds PV fragments directly (no P LDS roundtrip).
// PV computed as O^T = mfma(V^T, P^T) so q stays the lane dim (scalar alpha).
// Epilogue transposes O^T via the dead Qs buffer -> coalesced 16B stores.
// XCD swizzle: all 16 q-tiles of one (b,h) -> same XCD (K/V L2-resident).
// Q/K LDS XOR-swizzled: chunk' = chunk ^ (row&7). Vt: chunk ^ (d&7) ^ (d>>3)
// (write-conflict-free scatter; see r3 derivation).
__global__ __launch_bounds__(256) void attn_fwd(const half_t* __restrict__ qkv,
                                                half_t* __restrict__ o)
{
  __shared__ half_t Qs[128 * 64];
  __shared__ half_t KsBuf[2][64 * 64];
  __shared__ half_t VtBuf[2][64 * 64];   // V transposed: [d][kv]

  // XCD-aware remap: flat id f -> (bh, qt) s.t. same-bh blocks share an XCD
  const int f  = blockIdx.y * 16 + blockIdx.x;
  const int xcd = f & 7, i5 = f >> 3;
  const int bh = xcd + (i5 >> 4) * 8;    // 0..31
  const int qt = i5 & 15;                // 0..15
  const int b = bh >> 3, hd = bh & 7;

  const int tid = threadIdx.x;
  const int w = tid >> 6, lane = tid & 63;
  const int ql = lane & 31, hh = lane >> 5;

  const half_t* base = qkv + (size_t)(b * SEQ) * LDQKV;
  const int colq = hd * 64;
  const int colk = 512 + hd * 64;
  const int colv = 1024 + hd * 64;

  const int srow_l = lane >> 3, sch = lane & 7;
  const int vr0 = tid >> 3, vch = tid & 7;
  const int vr1 = (256 + tid) >> 3;

  // ---- prologue: stage Q + K(0) (gload_lds, pre-swizzled src); V(0) scatter
  #pragma unroll
  for (int c = 0; c < 4; ++c) {
    const int row = w * 32 + c * 8 + srow_l;
    const int cs = sch ^ (row & 7);
    load_lds16(base + (size_t)(qt * 128 + row) * LDQKV + colq + cs * 8,
               &Qs[(w * 32 + c * 8) * 64]);
  }
  half_t* ksc = KsBuf[0]; half_t* ksn = KsBuf[1];
  half_t* vtc = VtBuf[0]; half_t* vtn = VtBuf[1];
  #pragma unroll
  for (int c = 0; c < 2; ++c) {
    const int row = w * 16 + c * 8 + srow_l;
    const int cs = sch ^ (row & 7);
    load_lds16(base + (size_t)row * LDQKV + colk + cs * 8,
               &ksc[(w * 16 + c * 8) * 64]);
  }
  {
    half8 v0 = *(const half8*)(base + (size_t)vr0 * LDQKV + colv + vch * 8);
    half8 v1 = *(const half8*)(base + (size_t)vr1 * LDQKV + colv + vch * 8);
    #pragma unroll
    for (int j = 0; j < 8; ++j) {
      const int d = vch * 8 + j;
      const int fx = (d & 7) ^ (d >> 3);
      vtc[d * 64 + (((vr0 >> 3) ^ fx) << 3) + (vr0 & 7)] = v0[j];
      vtc[d * 64 + (((vr1 >> 3) ^ fx) << 3) + (vr1 & 7)] = v1[j];
    }
  }
  __syncthreads();

  // Q fragments (hoisted): B-operand of swapped QK^T. Lane holds
  // Q[q = w*32+ql][d = ks*16 + hh*8 + j]  (chunk = ks*2+hh, swizzled)
  half8 qf[4];
  #pragma unroll
  for (int ks = 0; ks < 4; ++ks) {
    const int row = w * 32 + ql;
    qf[ks] = *(const half8*)&Qs[row * 64 + (((ks * 2 + hh) ^ (row & 7)) << 3)];
  }

  float m_s = -3.0e38f, l_s = 0.0f;
  f32x16 acc0 = (f32x16)0.0f, acc1 = (f32x16)0.0f;   // O^T d-blocks 0,1

  const float sc = SCALE * 1.44269504089f;   // fold softmax scale, exp2 domain

  for (int t = 0; t < 32; ++t) {
    // ---- issue next tile staging into NXT buffers (hidden under compute)
    half8 vp0, vp1;
    if (t < 31) {
      const size_t nb = (size_t)((t + 1) * 64);
      vp0 = *(const half8*)(base + (nb + vr0) * LDQKV + colv + vch * 8);
      vp1 = *(const half8*)(base + (nb + vr1) * LDQKV + colv + vch * 8);
      #pragma unroll
      for (int c = 0; c < 2; ++c) {
        const int row = w * 16 + c * 8 + srow_l;
        const int cs = sch ^ (row & 7);
        load_lds16(base + (nb + row) * LDQKV + colk + cs * 8,
                   &ksn[(w * 16 + c * 8) * 64]);
      }
    }

    // ---- S^T = mfma(K, Q): s{kb}[reg] = S[k][q=ql],
    //      k = kb*32 + (reg&3) + 8*(reg>>2) + 4*hh
    f32x16 s0 = (f32x16)0.0f, s1 = (f32x16)0.0f;
    __builtin_amdgcn_s_setprio(1);
    #pragma unroll
    for (int ks = 0; ks < 4; ++ks) {
      const int c0 = ((ks * 2 + hh) ^ (ql & 7)) << 3;
      half8 kf0 = *(const half8*)&ksc[ql * 64 + c0];
      half8 kf1 = *(const half8*)&ksc[(32 + ql) * 64 + c0];
      s0 = __builtin_amdgcn_mfma_f32_32x32x16_f16(kf0, qf[ks], s0, 0, 0, 0);
      s1 = __builtin_amdgcn_mfma_f32_32x32x16_f16(kf1, qf[ks], s1, 0, 0, 0);
    }
    __builtin_amdgcn_s_setprio(0);

    // ---- online softmax: q = ql is lane-local -> scalar m/l/alpha.
    // T13 defer-max: skip rescale while max growth <= 8 (P bounded by 2^8).
    #pragma unroll
    for (int r = 0; r < 16; ++r) { s0[r] *= sc; s1[r] *= sc; }
    float vmax = s0[0];
    #pragma unroll
    for (int r = 1; r < 16; ++r) vmax = fmaxf(vmax, s0[r]);
    #pragma unroll
    for (int r = 0; r < 16; ++r) vmax = fmaxf(vmax, s1[r]);
    vmax = fmaxf(vmax, __shfl_xor(vmax, 32));
    if (!__all(vmax - m_s <= 8.0f)) {
      const float mnew = fmaxf(m_s, vmax);
      const float alpha = fast_exp2(m_s - mnew);
      m_s = mnew;
      l_s *= alpha;
      #pragma unroll
      for (int r = 0; r < 16; ++r) { acc0[r] *= alpha; acc1[r] *= alpha; }
    }
    #pragma unroll
    for (int r = 0; r < 16; ++r) {
      s0[r] = fast_exp2(s0[r] - m_s);
      s1[r] = fast_exp2(s1[r] - m_s);
    }
    float vsum = 0.0f;
    #pragma unroll
    for (int r = 0; r < 16; ++r) vsum += s0[r] + s1[r];
    vsum += __shfl_xor(vsum, 32);
    l_s += vsum;

    // ---- pack P -> f16 pairs (RNE): ph{kb}[p] holds k_local
    //      {8*(p>>1) + 4*hh + 2*(p&1), +1}
    u32 ph0[8], ph1[8];
    #pragma unroll
    for (int p = 0; p < 8; ++p) {
      half2v a; a[0] = (half_t)s0[2 * p]; a[1] = (half_t)s0[2 * p + 1];
      ph0[p] = __builtin_bit_cast(u32, a);
      half2v c; c[0] = (half_t)s1[2 * p]; c[1] = (half_t)s1[2 * p + 1];
      ph1[p] = __builtin_bit_cast(u32, c);
    }

    // ---- PV: O^T = mfma(V^T, P^T). P-frag per 16-k slice built by
    // cross-half exchange (shfl_xor 32) + cndmask (all indices static).
    auto PV = [&](u32 a0, u32 a1, u32 a2, u32 a3, int ks64) {
      const u32 sd0 = hh ? a0 : a2;
      const u32 sd1 = hh ? a1 : a3;
      const u32 o0 = (u32)__shfl_xor((int)sd0, 32);
      const u32 o1 = (u32)__shfl_xor((int)sd1, 32);
      u32x4 uq;
      uq[0] = hh ? o0 : a0;
      uq[1] = hh ? o1 : a1;
      uq[2] = hh ? a2 : o0;
      uq[3] = hh ? a3 : o1;
      const half8 pf = __builtin_bit_cast(half8, uq);
      const int c = ks64 * 2 + hh;
      const int d0 = ql;
      half8 vt0 = *(const half8*)&vtc[d0 * 64 + ((c ^ (d0 & 7) ^ (d0 >> 3)) << 3)];
      acc0 = __builtin_amdgcn_mfma_f32_32x32x16_f16(vt0, pf, acc0, 0, 0, 0);
      const int d1 = 32 + ql;
      half8 vt1 = *(const half8*)&vtc[d1 * 64 + ((c ^ (d1 & 7) ^ (d1 >> 3)) << 3)];
      acc1 = __builtin_amdgcn_mfma_f32_32x32x16_f16(vt1, pf, acc1, 0, 0, 0);
    };
    __builtin_amdgcn_s_setprio(1);
    PV(ph0[0], ph0[1], ph0[2], ph0[3], 0);
    PV(ph0[4], ph0[5], ph0[6], ph0[7], 1);
    PV(ph1[0], ph1[1], ph1[2], ph1[3], 2);
    PV(ph1[4], ph1[5], ph1[6], ph1[7], 3);
    __builtin_amdgcn_s_setprio(0);

    // ---- scatter prefetched V(t+1) into NXT (other buffer: no reader race)
    if (t < 31) {
      #pragma unroll
      for (int j = 0; j < 8; ++j) {
        const int d = vch * 8 + j;
        const int fx = (d & 7) ^ (d >> 3);
        vtn[d * 64 + (((vr0 >> 3) ^ fx) << 3) + (vr0 & 7)] = vp0[j];
        vtn[d * 64 + (((vr1 >> 3) ^ fx) << 3) + (vr1 & 7)] = vp1[j];
      }
    }
    __syncthreads();   // drains K(t+1) gload_lds + Vt writes; swap buffers
    half_t* tp = ksc; ksc = ksn; ksn = tp;
    tp = vtc; vtc = vtn; vtn = tp;
  }

  // ---- epilogue: O^T[d][q=ql] -> transpose via (dead, per-wave) Qs section
  const float inv = 1.0f / l_s;
  half_t* W = &Qs[w * 32 * 64];
  #pragma unroll
  for (int r = 0; r < 16; ++r) {
    const int dl = (r & 3) + 8 * (r >> 2) + 4 * hh;
    W[ql * 64 + (((dl >> 3) ^ (ql & 7)) << 3) + (dl & 7)] =
        (half_t)(acc0[r] * inv);
    const int dh = 32 + dl;
    W[ql * 64 + (((dh >> 3) ^ (ql & 7)) << 3) + (dh & 7)] =
        (half_t)(acc1[r] * inv);
  }
  asm volatile("s_waitcnt lgkmcnt(0)" ::: "memory");
  const int rr = lane >> 3, cc = lane & 7;
  #pragma unroll
  for (int p4 = 0; p4 < 4; ++p4) {
    const int row = p4 * 8 + rr;
    half8 v = *(const half8*)&W[row * 64 + ((cc ^ (row & 7)) << 3)];
    const int grow = b * SEQ + qt * 128 + w * 32 + row;
    *(half8*)&o[(size_t)grow * 512 + hd * 64 + cc * 8] = v;
  }
}

// ---------------------------------------------------------------------------
extern "C" void kernel_launch(void* const* d_in, const int* in_sizes, int n_in,
                              void* d_out, int out_size, void* d_ws, size_t ws_size,
                              hipStream_t stream)
{
  const float* x   = (const float*)d_in[0];
  const float* xp  = (const float*)d_in[1];
  const float* wq  = (const float*)d_in[2];
  const float* wkv = (const float*)d_in[3];
  const float* wo  = (const float*)d_in[4];
  const float* bo  = (const float*)d_in[5];
  float* out = (float*)d_out;

  half_t* ws   = (half_t*)d_ws;
  half_t* xh   = ws;                   // [8192][512]
  half_t* xph  = xh   + 4194304;       // [8192][512]
  half_t* wqt  = xph  + 4194304;       // [512][512]   (w_q^T)
  half_t* wkvt = wqt  + 262144;        // [1024][512]  (w_kv^T)
  half_t* wot  = wkvt + 524288;        // [512][512]   (w_out^T)
  half_t* qkvc = wot  + 262144;        // [8192][1536] q|k|v
  half_t* ows  = qkvc + 12582912;      // [8192][512]  attention out

  cvt2_f32_f16<<<8192, 256, 0, stream>>>(x, xp, xh, xph, 1048576);
  tcvt<<<dim3(16, 16), 256, 0, stream>>>(wq,  wqt,  512);
  tcvt<<<dim3(32, 16), 256, 0, stream>>>(wkv, wkvt, 1024);
  tcvt<<<dim3(16, 16), 256, 0, stream>>>(wo,  wot,  512);

  gemm_bt<0><<<dim3(64, 12), 256, 0, stream>>>(xh, xph, wqt, wkvt, qkvc,
                                               nullptr, nullptr);
  attn_fwd<<<dim3(16, 32), 256, 0, stream>>>(qkvc, ows);
  gemm_bt<1><<<dim3(64, 4), 256, 0, stream>>>(ows, nullptr, wot, nullptr,
                                              nullptr, bo, out);
}